// Round 3
// baseline (3244.130 us; speedup 1.0000x reference)
//
#include <hip/hip_runtime.h>
#include <math.h>

#define H 224
#define W 224
#define C 196
#define NB 10
#define NUM_ITERS 50
#define B 64
#define HW (H*W)
#define GRAD_WEIGHT 10.0f
#define COLOR_WEIGHT 10.0f

// ---------------- grad map + wgm ----------------
__global__ void grad_kernel(const float* __restrict__ x, const float* __restrict__ wgt,
                            float* __restrict__ wgm, float* __restrict__ out_grad) {
    int idx = blockIdx.x * blockDim.x + threadIdx.x;
    if (idx >= B * HW) return;
    int b = idx / HW;
    int p = idx - b * HW;
    int h = p / W, w = p - (p / W) * W;
    const float* xb = x + (size_t)b * 3 * HW;
    float acc_x = 0.f, acc_y = 0.f;
    #pragma unroll
    for (int ky = 0; ky < 3; ky++) {
        #pragma unroll
        for (int kx = 0; kx < 3; kx++) {
            int hh = h + ky - 1, ww = w + kx - 1;
            float g = 0.f;
            if (hh >= 0 && hh < H && ww >= 0 && ww < W) {
                int q = hh * W + ww;
                float r  = xb[q];
                float gg = xb[HW + q];
                float bl = xb[2 * HW + q];
                g = __fadd_rn(__fadd_rn(__fmul_rn(0.2989f, r), __fmul_rn(0.587f, gg)),
                              __fmul_rn(0.114f, bl));
            }
            float wx = wgt[ky * 3 + kx];
            float wy = wgt[9 + ky * 3 + kx];
            acc_x = __fadd_rn(acc_x, __fmul_rn(wx, g));
            acc_y = __fadd_rn(acc_y, __fmul_rn(wy, g));
        }
    }
    float s = __fadd_rn(__fadd_rn(__fmul_rn(acc_x, acc_x), __fmul_rn(acc_y, acc_y)), 1e-8f);
    float gv = sqrtf(s);
    out_grad[idx] = gv;
    wgm[idx] = __fmul_rn(powf(gv, 4.0f), GRAD_WEIGHT);
}

// ---------------- color diffs (4 dirs, toroidal roll) ----------------
__global__ void cdiff_kernel(const float* __restrict__ x, float* __restrict__ cdiffs) {
    int idx = blockIdx.x * blockDim.x + threadIdx.x;
    if (idx >= B * HW) return;
    int b = idx / HW;
    int p = idx - b * HW;
    int h = p / W, w = p - (p / W) * W;
    const int dys[4] = {-1, 1, 0, 0};
    const int dxs[4] = {0, 0, -1, 1};
    const float* xb = x + (size_t)b * 3 * HW;
    float r0 = xb[p];
    float g0 = xb[HW + p];
    float b0 = xb[2 * HW + p];
    #pragma unroll
    for (int d = 0; d < 4; d++) {
        int hh = h - dys[d]; hh += (hh < 0) ? H : 0; hh -= (hh >= H) ? H : 0;
        int ww = w - dxs[d]; ww += (ww < 0) ? W : 0; ww -= (ww >= W) ? W : 0;
        int q = hh * W + ww;
        float dr = fabsf(__fsub_rn(r0, xb[q]));
        float dg = fabsf(__fsub_rn(g0, xb[HW + q]));
        float db = fabsf(__fsub_rn(b0, xb[2 * HW + q]));
        float sum = __fadd_rn(__fadd_rn(dr, dg), db);
        cdiffs[(size_t)d * B * HW + idx] = sum;
    }
}

// ---------------- sequential centroid relocation scan ----------------
__global__ void scan_kernel(const float* __restrict__ grad,
                            int* __restrict__ cents_i, float* __restrict__ out_cents) {
    __shared__ unsigned char occ[HW];
    int b = blockIdx.x;
    int lane = threadIdx.x;  // 64 threads = one wave
    for (int i = lane; i < HW; i += 64) occ[i] = 0;
    __syncthreads();
    const float* gb = grad + (size_t)b * HW;
    for (int c = 0; c < C; c++) {
        int cy = 8 + 16 * (c / 14), cx = 8 + 16 * (c % 14);
        int ymin = max(0, cy - NB), ymax = min(H, cy + NB);
        int xmin = max(0, cx - NB), xmax = min(W, cx + NB);
        int rh = ymax - ymin, rw = xmax - xmin;
        float v[7];
        float lmin = INFINITY;
        #pragma unroll
        for (int i = 0; i < 7; i++) {
            int cell = lane + 64 * i;
            float val = INFINITY;
            if (cell < 400) {
                int r = cell / 20, cc = cell - (cell / 20) * 20;
                if (r < rh && cc < rw) val = gb[(ymin + r) * W + xmin + cc];
            }
            v[i] = val;
            lmin = fminf(lmin, val);
        }
        #pragma unroll
        for (int m = 1; m < 64; m <<= 1) lmin = fminf(lmin, __shfl_xor(lmin, m, 64));
        float mv = lmin;
        int lidx = 0x7fffffff;
        #pragma unroll
        for (int i = 0; i < 7; i++) {
            int cell = lane + 64 * i;
            if (cell < 400 && v[i] == mv) {
                int r = cell / 20, cc = cell - (cell / 20) * 20;
                if (!occ[(ymin + r) * W + xmin + cc]) lidx = min(lidx, cell);
            }
        }
        #pragma unroll
        for (int m = 1; m < 64; m <<= 1) lidx = min(lidx, __shfl_xor(lidx, m, 64));
        int ny, nx;
        if (lidx != 0x7fffffff) { ny = ymin + lidx / 20; nx = xmin + lidx % 20; }
        else { ny = cy; nx = cx; }
        if (lane == 0) {
            if (lidx != 0x7fffffff) occ[ny * W + nx] = 1;
            cents_i[(b * C + c) * 2 + 0] = ny;
            cents_i[(b * C + c) * 2 + 1] = nx;
            out_cents[(b * C + c) * 2 + 0] = (float)ny;
            out_cents[(b * C + c) * 2 + 1] = (float)nx;
        }
        __syncthreads();
    }
}

// ---------------- propagation init / seed / pass / finalize ----------------
__global__ void init_kernel(float* __restrict__ dist, short* __restrict__ mask) {
    int idx = blockIdx.x * blockDim.x + threadIdx.x;
    if (idx >= B * HW) return;
    dist[idx] = INFINITY;
    mask[idx] = -1;
}

__global__ void seed_kernel(const int* __restrict__ cents_i,
                            float* __restrict__ dist, short* __restrict__ mask) {
    int b = threadIdx.x;
    if (b >= B) return;
    for (int c = 0; c < C; c++) {
        int cy = cents_i[(b * C + c) * 2 + 0];
        int cx = cents_i[(b * C + c) * 2 + 1];
        size_t q = (size_t)b * HW + cy * W + cx;
        dist[q] = 0.f;
        mask[q] = (short)c;
    }
}

__global__ void pass_kernel(const float* __restrict__ din, const short* __restrict__ min_,
                            float* __restrict__ dout, short* __restrict__ mout,
                            const float* __restrict__ wgm, const float* __restrict__ cdiff,
                            int dy, int dx) {
    int idx = blockIdx.x * blockDim.x + threadIdx.x;
    if (idx >= B * HW) return;
    int b = idx / HW;
    int p = idx - b * HW;
    int h = p / W, w = p - (p / W) * W;
    int hs = h - dy; hs += (hs < 0) ? H : 0; hs -= (hs >= H) ? H : 0;
    int ws2 = w - dx; ws2 += (ws2 < 0) ? W : 0; ws2 -= (ws2 >= W) ? W : 0;
    size_t src = (size_t)b * HW + hs * W + ws2;
    float sd = din[src];
    float d0 = din[idx];
    float wd = __fadd_rn(__fadd_rn(sd, wgm[idx]), __fmul_rn(cdiff[idx], COLOR_WEIGHT));
    bool upd = wd < d0;
    dout[idx] = upd ? wd : d0;
    mout[idx] = upd ? min_[src] : min_[idx];
}

__global__ void finalize_kernel(const short* __restrict__ mask, float* __restrict__ out_mask) {
    int idx = blockIdx.x * blockDim.x + threadIdx.x;
    if (idx >= B * HW) return;
    out_mask[idx] = (float)mask[idx];
}

extern "C" void kernel_launch(void* const* d_in, const int* in_sizes, int n_in,
                              void* d_out, int out_size, void* d_ws, size_t ws_size,
                              hipStream_t stream) {
    const float* x   = (const float*)d_in[0];
    const float* wgt = (const float*)d_in[1];
    float* out = (float*)d_out;
    float* out_grad  = out;
    float* out_cents = out + (size_t)B * HW;
    float* out_mask  = out + (size_t)B * HW + (size_t)B * C * 2;

    char* ws = (char*)d_ws;
    const size_t n = (size_t)B * HW;
    float* wgm    = (float*)ws;                ws += sizeof(float) * n;
    float* cdiffs = (float*)ws;                ws += sizeof(float) * n * 4;
    float* dist_a = (float*)ws;                ws += sizeof(float) * n;
    float* dist_b = (float*)ws;                ws += sizeof(float) * n;
    short* mask_a = (short*)ws;                ws += sizeof(short) * n;
    short* mask_b = (short*)ws;                ws += sizeof(short) * n;
    int*   cents_i = (int*)ws;                 ws += sizeof(int) * B * C * 2;

    dim3 blk(256);
    dim3 grd((unsigned)((n + 255) / 256));

    grad_kernel<<<grd, blk, 0, stream>>>(x, wgt, wgm, out_grad);
    cdiff_kernel<<<grd, blk, 0, stream>>>(x, cdiffs);
    scan_kernel<<<B, 64, 0, stream>>>(out_grad, cents_i, out_cents);
    init_kernel<<<grd, blk, 0, stream>>>(dist_a, mask_a);
    seed_kernel<<<1, 64, 0, stream>>>(cents_i, dist_a, mask_a);

    const int dys[4] = {-1, 1, 0, 0};
    const int dxs[4] = {0, 0, -1, 1};
    float* da = dist_a; float* db = dist_b;
    short* ma = mask_a; short* mb = mask_b;
    for (int it = 0; it < NUM_ITERS; it++) {
        for (int d = 0; d < 4; d++) {
            pass_kernel<<<grd, blk, 0, stream>>>(da, ma, db, mb, wgm,
                                                 cdiffs + (size_t)d * n, dys[d], dxs[d]);
            float* td = da; da = db; db = td;
            short* tm = ma; ma = mb; mb = tm;
        }
    }
    finalize_kernel<<<grd, blk, 0, stream>>>(ma, out_mask);
}

// Round 4
// 645.378 us; speedup vs baseline: 5.0267x; 5.0267x over previous
//
#include <hip/hip_runtime.h>
#include <math.h>

#define H 224
#define W 224
#define C 196
#define NB 10
#define NUM_ITERS 50
#define B 64
#define HW (H*W)
#define TS 56
#define KCAND 8
#define COLOR_WEIGHT 10.0f
#define GRAD_WEIGHT 10.0f

// ---------------- grad map + wgm (unchanged numerics, PASSED round 3) ----------------
__global__ void grad_kernel(const float* __restrict__ x, const float* __restrict__ wgt,
                            float* __restrict__ wgm, float* __restrict__ out_grad) {
    int idx = blockIdx.x * blockDim.x + threadIdx.x;
    if (idx >= B * HW) return;
    int b = idx / HW;
    int p = idx - b * HW;
    int h = p / W, w = p - (p / W) * W;
    const float* xb = x + (size_t)b * 3 * HW;
    float acc_x = 0.f, acc_y = 0.f;
    #pragma unroll
    for (int ky = 0; ky < 3; ky++) {
        #pragma unroll
        for (int kx = 0; kx < 3; kx++) {
            int hh = h + ky - 1, ww = w + kx - 1;
            float g = 0.f;
            if (hh >= 0 && hh < H && ww >= 0 && ww < W) {
                int q = hh * W + ww;
                float r  = xb[q];
                float gg = xb[HW + q];
                float bl = xb[2 * HW + q];
                g = __fadd_rn(__fadd_rn(__fmul_rn(0.2989f, r), __fmul_rn(0.587f, gg)),
                              __fmul_rn(0.114f, bl));
            }
            float wx = wgt[ky * 3 + kx];
            float wy = wgt[9 + ky * 3 + kx];
            acc_x = __fadd_rn(acc_x, __fmul_rn(wx, g));
            acc_y = __fadd_rn(acc_y, __fmul_rn(wy, g));
        }
    }
    float s = __fadd_rn(__fadd_rn(__fmul_rn(acc_x, acc_x), __fmul_rn(acc_y, acc_y)), 1e-8f);
    float gv = sqrtf(s);
    out_grad[idx] = gv;
    wgm[idx] = __fmul_rn(powf(gv, 4.0f), GRAD_WEIGHT);
}

// ---------------- cw[d] = cdiff[d] * COLOR_WEIGHT (same bits as reference path) ----------------
__global__ void cw_kernel(const float* __restrict__ x, float* __restrict__ cw) {
    int idx = blockIdx.x * blockDim.x + threadIdx.x;
    if (idx >= B * HW) return;
    int b = idx / HW;
    int p = idx - b * HW;
    int h = p / W, w = p - (p / W) * W;
    const int dys[4] = {-1, 1, 0, 0};
    const int dxs[4] = {0, 0, -1, 1};
    const float* xb = x + (size_t)b * 3 * HW;
    float r0 = xb[p];
    float g0 = xb[HW + p];
    float b0 = xb[2 * HW + p];
    #pragma unroll
    for (int d = 0; d < 4; d++) {
        int hh = h - dys[d]; hh += (hh < 0) ? H : 0; hh -= (hh >= H) ? H : 0;
        int ww = w - dxs[d]; ww += (ww < 0) ? W : 0; ww -= (ww >= W) ? W : 0;
        int q = hh * W + ww;
        float dr = fabsf(__fsub_rn(r0, xb[q]));
        float dg = fabsf(__fsub_rn(g0, xb[HW + q]));
        float db = fabsf(__fsub_rn(b0, xb[2 * HW + q]));
        float sum = __fadd_rn(__fadd_rn(dr, dg), db);
        cw[(size_t)d * B * HW + idx] = __fmul_rn(sum, COLOR_WEIGHT);
    }
}

// ---------------- parallel per-centroid window argmin (candidates) ----------------
__global__ void cand_kernel(const float* __restrict__ grad, int* __restrict__ cand,
                            int* __restrict__ cnt) {
    int gtid = blockIdx.x * blockDim.x + threadIdx.x;
    int wid = gtid >> 6;
    int lane = threadIdx.x & 63;
    if (wid >= B * C) return;
    int b = wid / C, c = wid - b * C;
    const float* gb = grad + (size_t)b * HW;
    int cy = 8 + 16 * (c / 14), cx = 8 + 16 * (c % 14);
    int ymin = max(0, cy - NB), ymax = min(H, cy + NB);
    int xmin = max(0, cx - NB), xmax = min(W, cx + NB);
    int rh = ymax - ymin, rw = xmax - xmin;
    float v[7];
    float lmin = INFINITY;
    #pragma unroll
    for (int i = 0; i < 7; i++) {
        int cell = lane + 64 * i;
        float val = INFINITY;
        if (cell < 400) {
            int r = cell / 20, cc = cell - (cell / 20) * 20;
            if (r < rh && cc < rw) val = gb[(ymin + r) * W + xmin + cc];
        }
        v[i] = val;
        lmin = fminf(lmin, val);
    }
    #pragma unroll
    for (int m = 1; m < 64; m <<= 1) lmin = fminf(lmin, __shfl_xor(lmin, m, 64));
    float mv = lmin;
    int n = 0;
    int base = wid * KCAND;
    #pragma unroll
    for (int i = 0; i < 7; i++) {
        unsigned long long msk = __ballot(v[i] == mv);
        if (lane == 0) {
            while (msk) {
                int bit = __ffsll(msk) - 1;
                msk &= msk - 1;
                int cell = bit + 64 * i;
                if (n < KCAND) {
                    int r = cell / 20, cc = cell - (cell / 20) * 20;
                    cand[base + n] = (ymin + r) * W + (xmin + cc);
                }
                n++;
            }
        }
    }
    if (lane == 0) cnt[wid] = n;
}

// ---------------- sequential occupancy resolve (LDS-only fast path) ----------------
__global__ void resolve_kernel(const float* __restrict__ grad,
                               const int* __restrict__ cand, const int* __restrict__ cnt,
                               int* __restrict__ cents_i, float* __restrict__ out_cents) {
    __shared__ unsigned char occ[HW];
    __shared__ int scand[C * KCAND];
    __shared__ int scnt[C];
    int b = blockIdx.x;
    int lane = threadIdx.x;
    for (int i = lane; i < HW / 4; i += 64) ((int*)occ)[i] = 0;
    for (int i = lane; i < C * KCAND; i += 64) scand[i] = cand[b * C * KCAND + i];
    for (int i = lane; i < C; i += 64) scnt[i] = cnt[b * C + i];
    __syncthreads();
    if (lane == 0) {
        const float* gb = grad + (size_t)b * HW;
        for (int c = 0; c < C; c++) {
            int n = scnt[c];
            int ny = 0, nx = 0;
            bool found = false;
            if (n <= KCAND) {
                for (int k = 0; k < n; k++) {
                    int pos = scand[c * KCAND + k];
                    if (!occ[pos]) {
                        found = true; ny = pos / W; nx = pos - (pos / W) * W;
                        occ[pos] = 1; break;
                    }
                }
            } else {
                // slow path (>KCAND exact ties — effectively never)
                int cy = 8 + 16 * (c / 14), cx = 8 + 16 * (c % 14);
                int ymin = max(0, cy - NB), ymax = min(H, cy + NB);
                int xmin = max(0, cx - NB), xmax = min(W, cx + NB);
                float mv = INFINITY;
                for (int r = ymin; r < ymax; r++)
                    for (int cc = xmin; cc < xmax; cc++)
                        mv = fminf(mv, gb[r * W + cc]);
                for (int r = ymin; r < ymax && !found; r++)
                    for (int cc = xmin; cc < xmax && !found; cc++)
                        if (gb[r * W + cc] == mv && !occ[r * W + cc]) {
                            found = true; ny = r; nx = cc; occ[r * W + cc] = 1;
                        }
            }
            if (!found) { ny = 8 + 16 * (c / 14); nx = 8 + 16 * (c % 14); }
            cents_i[(b * C + c) * 2 + 0] = ny;
            cents_i[(b * C + c) * 2 + 1] = nx;
            out_cents[(b * C + c) * 2 + 0] = (float)ny;
            out_cents[(b * C + c) * 2 + 1] = (float)nx;
        }
    }
}

// ---------------- propagation init / seed ----------------
__global__ void init_kernel(float* __restrict__ dist, short* __restrict__ mask) {
    int idx = blockIdx.x * blockDim.x + threadIdx.x;
    if (idx >= B * HW) return;
    dist[idx] = INFINITY;
    mask[idx] = -1;
}

__global__ void seed_kernel(const int* __restrict__ cents_i,
                            float* __restrict__ dist, short* __restrict__ mask) {
    int b = threadIdx.x;
    if (b >= B) return;
    for (int c = 0; c < C; c++) {
        int cy = cents_i[(b * C + c) * 2 + 0];
        int cx = cents_i[(b * C + c) * 2 + 1];
        size_t q = (size_t)b * HW + cy * W + cx;
        dist[q] = 0.f;
        mask[q] = (short)c;
    }
}

// ---------------- fused propagation: T iterations, register time-skewing ----------------
__device__ __forceinline__ int wrapc(int v) {
    v += (v < 0) ? 224 : 0;
    v -= (v >= 224) ? 224 : 0;
    return v;
}
__device__ __forceinline__ uint2 packm(int a, int b_, int c_, int d_) {
    uint2 r;
    r.x = (a & 0xffff) | (b_ << 16);
    r.y = (c_ & 0xffff) | (d_ << 16);
    return r;
}

template<int DIR>
__device__ __forceinline__ void do_pass(float (&D)[4][4], int (&M)[4][4],
    const float (&Wg)[4][4], const float* __restrict__ cwd, const int (&rowoff)[4],
    float4* __restrict__ hd, uint2* __restrict__ hm, int tid, int ty, int tx)
{
    // publish pre-pass boundary values
    float4 pd; uint2 pm;
    if      (DIR == 0) { pd = make_float4(D[0][0],D[0][1],D[0][2],D[0][3]); pm = packm(M[0][0],M[0][1],M[0][2],M[0][3]); }
    else if (DIR == 1) { pd = make_float4(D[3][0],D[3][1],D[3][2],D[3][3]); pm = packm(M[3][0],M[3][1],M[3][2],M[3][3]); }
    else if (DIR == 2) { pd = make_float4(D[0][0],D[1][0],D[2][0],D[3][0]); pm = packm(M[0][0],M[1][0],M[2][0],M[3][0]); }
    else               { pd = make_float4(D[0][3],D[1][3],D[2][3],D[3][3]); pm = packm(M[0][3],M[1][3],M[2][3],M[3][3]); }
    hd[tid] = pd; hm[tid] = pm;
    __syncthreads();
    bool has; int nidx;
    if      (DIR == 0) { has = (ty < 15); nidx = tid + 16; }
    else if (DIR == 1) { has = (ty > 0);  nidx = tid - 16; }
    else if (DIR == 2) { has = (tx < 15); nidx = tid + 1; }
    else               { has = (tx > 0);  nidx = tid - 1; }
    float nb[4]; int nbm[4];
    if (has) {
        float4 t = hd[nidx]; uint2 u = hm[nidx];
        nb[0] = t.x; nb[1] = t.y; nb[2] = t.z; nb[3] = t.w;
        nbm[0] = (int)(short)(u.x & 0xffff); nbm[1] = (int)(short)(u.x >> 16);
        nbm[2] = (int)(short)(u.y & 0xffff); nbm[3] = (int)(short)(u.y >> 16);
    } else {
        nb[0] = nb[1] = nb[2] = nb[3] = INFINITY;
        nbm[0] = nbm[1] = nbm[2] = nbm[3] = 0;
    }
    float cv[4][4];
    #pragma unroll
    for (int i = 0; i < 4; i++) {
        float4 t = *(const float4*)(cwd + rowoff[i]);
        cv[i][0] = t.x; cv[i][1] = t.y; cv[i][2] = t.z; cv[i][3] = t.w;
    }
    // in-register update in anti-propagation order (pre-value semantics, no dbuf)
    if (DIR == 0) {
        #pragma unroll
        for (int i = 0; i < 4; i++)
            #pragma unroll
            for (int j = 0; j < 4; j++) {
                float sd = (i < 3) ? D[i+1][j] : nb[j];
                int   sm = (i < 3) ? M[i+1][j] : nbm[j];
                float wd = __fadd_rn(__fadd_rn(sd, Wg[i][j]), cv[i][j]);
                if (wd < D[i][j]) { D[i][j] = wd; M[i][j] = sm; }
            }
    } else if (DIR == 1) {
        #pragma unroll
        for (int i = 3; i >= 0; i--)
            #pragma unroll
            for (int j = 0; j < 4; j++) {
                float sd = (i > 0) ? D[i-1][j] : nb[j];
                int   sm = (i > 0) ? M[i-1][j] : nbm[j];
                float wd = __fadd_rn(__fadd_rn(sd, Wg[i][j]), cv[i][j]);
                if (wd < D[i][j]) { D[i][j] = wd; M[i][j] = sm; }
            }
    } else if (DIR == 2) {
        #pragma unroll
        for (int i = 0; i < 4; i++)
            #pragma unroll
            for (int j = 0; j < 4; j++) {
                float sd = (j < 3) ? D[i][j+1] : nb[i];
                int   sm = (j < 3) ? M[i][j+1] : nbm[i];
                float wd = __fadd_rn(__fadd_rn(sd, Wg[i][j]), cv[i][j]);
                if (wd < D[i][j]) { D[i][j] = wd; M[i][j] = sm; }
            }
    } else {
        #pragma unroll
        for (int i = 0; i < 4; i++)
            #pragma unroll
            for (int j = 3; j >= 0; j--) {
                float sd = (j > 0) ? D[i][j-1] : nb[i];
                int   sm = (j > 0) ? M[i][j-1] : nbm[i];
                float wd = __fadd_rn(__fadd_rn(sd, Wg[i][j]), cv[i][j]);
                if (wd < D[i][j]) { D[i][j] = wd; M[i][j] = sm; }
            }
    }
}

__global__ __launch_bounds__(256) void prop_fused(
    const float* __restrict__ din, const short* __restrict__ min_,
    float* __restrict__ dout, short* __restrict__ mout,
    const float* __restrict__ wgm, const float* __restrict__ cw, int n_it)
{
    __shared__ float4 hd[2][256];
    __shared__ uint2  hm[2][256];
    int blk = blockIdx.x;
    int b = blk >> 4, tile = blk & 15;
    int ty0 = (tile >> 2) * TS, tx0 = (tile & 3) * TS;
    int tid = threadIdx.x;
    int tx = tid & 15, ty = tid >> 4;
    int gx0 = wrapc(tx0 + 4 * tx - 4);
    int rowoff[4];
    #pragma unroll
    for (int i = 0; i < 4; i++) {
        int y = wrapc(ty0 + 4 * ty - 4 + i);
        rowoff[i] = y * W + gx0;
    }
    const float* dinb = din + (size_t)b * HW;
    const short* minb = min_ + (size_t)b * HW;
    const float* wgmb = wgm + (size_t)b * HW;
    float D[4][4]; int M[4][4]; float Wg[4][4];
    #pragma unroll
    for (int i = 0; i < 4; i++) {
        float4 dv = *(const float4*)(dinb + rowoff[i]);
        float4 wv = *(const float4*)(wgmb + rowoff[i]);
        uint2  mv = *(const uint2*)(minb + rowoff[i]);
        D[i][0] = dv.x; D[i][1] = dv.y; D[i][2] = dv.z; D[i][3] = dv.w;
        Wg[i][0] = wv.x; Wg[i][1] = wv.y; Wg[i][2] = wv.z; Wg[i][3] = wv.w;
        M[i][0] = (int)(short)(mv.x & 0xffff); M[i][1] = (int)(short)(mv.x >> 16);
        M[i][2] = (int)(short)(mv.y & 0xffff); M[i][3] = (int)(short)(mv.y >> 16);
    }
    const float* cw0 = cw + (size_t)b * HW;
    const float* cw1 = cw0 + (size_t)B * HW;
    const float* cw2 = cw1 + (size_t)B * HW;
    const float* cw3 = cw2 + (size_t)B * HW;
    for (int it = 0; it < n_it; ++it) {
        do_pass<0>(D, M, Wg, cw0, rowoff, hd[0], hm[0], tid, ty, tx);
        do_pass<1>(D, M, Wg, cw1, rowoff, hd[1], hm[1], tid, ty, tx);
        do_pass<2>(D, M, Wg, cw2, rowoff, hd[0], hm[0], tid, ty, tx);
        do_pass<3>(D, M, Wg, cw3, rowoff, hd[1], hm[1], tid, ty, tx);
    }
    if (ty >= 1 && ty < 15 && tx >= 1 && tx < 15) {
        float* doutb = dout + (size_t)b * HW;
        short* moutb = mout + (size_t)b * HW;
        #pragma unroll
        for (int i = 0; i < 4; i++) {
            *(float4*)(doutb + rowoff[i]) = make_float4(D[i][0], D[i][1], D[i][2], D[i][3]);
            *(uint2*)(moutb + rowoff[i]) = packm(M[i][0], M[i][1], M[i][2], M[i][3]);
        }
    }
}

__global__ void finalize_kernel(const short* __restrict__ mask, float* __restrict__ out_mask) {
    int idx = blockIdx.x * blockDim.x + threadIdx.x;
    if (idx >= B * HW) return;
    out_mask[idx] = (float)mask[idx];
}

extern "C" void kernel_launch(void* const* d_in, const int* in_sizes, int n_in,
                              void* d_out, int out_size, void* d_ws, size_t ws_size,
                              hipStream_t stream) {
    const float* x   = (const float*)d_in[0];
    const float* wgt = (const float*)d_in[1];
    float* out = (float*)d_out;
    float* out_grad  = out;
    float* out_cents = out + (size_t)B * HW;
    float* out_mask  = out + (size_t)B * HW + (size_t)B * C * 2;

    char* ws = (char*)d_ws;
    const size_t n = (size_t)B * HW;
    float* wgm    = (float*)ws;                ws += sizeof(float) * n;
    float* cw     = (float*)ws;                ws += sizeof(float) * n * 4;
    float* dist_a = (float*)ws;                ws += sizeof(float) * n;
    float* dist_b = (float*)ws;                ws += sizeof(float) * n;
    short* mask_a = (short*)ws;                ws += sizeof(short) * n;
    short* mask_b = (short*)ws;                ws += sizeof(short) * n;
    int*   cents_i = (int*)ws;                 ws += sizeof(int) * B * C * 2;
    // cand/cnt alias dist_b: only live between cand_kernel and resolve_kernel,
    // before the first prop_fused write of dist_b.
    int* cand = (int*)dist_b;
    int* cnt  = cand + (size_t)B * C * KCAND;

    dim3 blk(256);
    dim3 grd((unsigned)((n + 255) / 256));

    grad_kernel<<<grd, blk, 0, stream>>>(x, wgt, wgm, out_grad);
    cw_kernel<<<grd, blk, 0, stream>>>(x, cw);
    cand_kernel<<<(B * C) / 4, 256, 0, stream>>>(out_grad, cand, cnt);
    resolve_kernel<<<B, 64, 0, stream>>>(out_grad, cand, cnt, cents_i, out_cents);
    init_kernel<<<grd, blk, 0, stream>>>(dist_a, mask_a);
    seed_kernel<<<1, 64, 0, stream>>>(cents_i, dist_a, mask_a);

    float* da = dist_a; float* db = dist_b;
    short* ma = mask_a; short* mb = mask_b;
    int iters_left = NUM_ITERS;
    while (iters_left > 0) {
        int n_it = iters_left < 4 ? iters_left : 4;
        prop_fused<<<B * 16, 256, 0, stream>>>(da, ma, db, mb, wgm, cw, n_it);
        float* td = da; da = db; db = td;
        short* tm = ma; ma = mb; mb = tm;
        iters_left -= n_it;
    }
    finalize_kernel<<<grd, blk, 0, stream>>>(ma, out_mask);
}

// Round 5
// 585.283 us; speedup vs baseline: 5.5428x; 1.1027x over previous
//
#include <hip/hip_runtime.h>
#include <math.h>

#define H 224
#define W 224
#define C 196
#define NB 10
#define NUM_ITERS 50
#define B 64
#define HW (H*W)
#define TS 56
#define KCAND 8
#define COLOR_WEIGHT 10.0f
#define GRAD_WEIGHT 10.0f

// ---------------- fused grad map + wgm + cw ----------------
__global__ void gradcw_kernel(const float* __restrict__ x, const float* __restrict__ wgt,
                              float* __restrict__ wgm, float* __restrict__ out_grad,
                              float* __restrict__ cw) {
    int idx = blockIdx.x * blockDim.x + threadIdx.x;
    if (idx >= B * HW) return;
    int b = idx / HW;
    int p = idx - b * HW;
    int h = p / W, w = p - (p / W) * W;
    const float* xb = x + (size_t)b * 3 * HW;
    float acc_x = 0.f, acc_y = 0.f;
    #pragma unroll
    for (int ky = 0; ky < 3; ky++) {
        #pragma unroll
        for (int kx = 0; kx < 3; kx++) {
            int hh = h + ky - 1, ww = w + kx - 1;
            float g = 0.f;
            if (hh >= 0 && hh < H && ww >= 0 && ww < W) {
                int q = hh * W + ww;
                g = __fadd_rn(__fadd_rn(__fmul_rn(0.2989f, xb[q]), __fmul_rn(0.587f, xb[HW + q])),
                              __fmul_rn(0.114f, xb[2 * HW + q]));
            }
            acc_x = __fadd_rn(acc_x, __fmul_rn(wgt[ky * 3 + kx], g));
            acc_y = __fadd_rn(acc_y, __fmul_rn(wgt[9 + ky * 3 + kx], g));
        }
    }
    float s = __fadd_rn(__fadd_rn(__fmul_rn(acc_x, acc_x), __fmul_rn(acc_y, acc_y)), 1e-8f);
    float gv = sqrtf(s);
    out_grad[idx] = gv;
    wgm[idx] = __fmul_rn(powf(gv, 4.0f), GRAD_WEIGHT);

    const int dys[4] = {-1, 1, 0, 0};
    const int dxs[4] = {0, 0, -1, 1};
    float r0 = xb[p];
    float g0 = xb[HW + p];
    float b0 = xb[2 * HW + p];
    #pragma unroll
    for (int d = 0; d < 4; d++) {
        int hh = h - dys[d]; hh += (hh < 0) ? H : 0; hh -= (hh >= H) ? H : 0;
        int ww = w - dxs[d]; ww += (ww < 0) ? W : 0; ww -= (ww >= W) ? W : 0;
        int q = hh * W + ww;
        float dr = fabsf(__fsub_rn(r0, xb[q]));
        float dg = fabsf(__fsub_rn(g0, xb[HW + q]));
        float db = fabsf(__fsub_rn(b0, xb[2 * HW + q]));
        float sum = __fadd_rn(__fadd_rn(dr, dg), db);
        cw[(size_t)d * B * HW + idx] = __fmul_rn(sum, COLOR_WEIGHT);
    }
}

// ---------------- parallel per-centroid window argmin (candidates) ----------------
__global__ void cand_kernel(const float* __restrict__ grad, int* __restrict__ cand,
                            int* __restrict__ cnt) {
    int gtid = blockIdx.x * blockDim.x + threadIdx.x;
    int wid = gtid >> 6;
    int lane = threadIdx.x & 63;
    if (wid >= B * C) return;
    int b = wid / C, c = wid - b * C;
    const float* gb = grad + (size_t)b * HW;
    int cy = 8 + 16 * (c / 14), cx = 8 + 16 * (c % 14);
    int ymin = max(0, cy - NB), ymax = min(H, cy + NB);
    int xmin = max(0, cx - NB), xmax = min(W, cx + NB);
    int rh = ymax - ymin, rw = xmax - xmin;
    float v[7];
    float lmin = INFINITY;
    #pragma unroll
    for (int i = 0; i < 7; i++) {
        int cell = lane + 64 * i;
        float val = INFINITY;
        if (cell < 400) {
            int r = cell / 20, cc = cell - (cell / 20) * 20;
            if (r < rh && cc < rw) val = gb[(ymin + r) * W + xmin + cc];
        }
        v[i] = val;
        lmin = fminf(lmin, val);
    }
    #pragma unroll
    for (int m = 1; m < 64; m <<= 1) lmin = fminf(lmin, __shfl_xor(lmin, m, 64));
    float mv = lmin;
    int n = 0;
    int base = wid * KCAND;
    #pragma unroll
    for (int i = 0; i < 7; i++) {
        unsigned long long msk = __ballot(v[i] == mv);
        if (lane == 0) {
            while (msk) {
                int bit = __ffsll(msk) - 1;
                msk &= msk - 1;
                int cell = bit + 64 * i;
                if (n < KCAND) {
                    int r = cell / 20, cc = cell - (cell / 20) * 20;
                    cand[base + n] = (ymin + r) * W + (xmin + cc);
                }
                n++;
            }
        }
    }
    if (lane == 0) cnt[wid] = n;
}

// ---------------- wavefront-parallel occupancy resolve ----------------
// Windows of centroids (gi,gj) and (gi',gj') overlap iff |dgi|<=1 && |dgj|<=1.
// Round r = 2*gi + gj: all overlapping smaller-index neighbors are in strictly
// earlier rounds; same-round actives have |dgj|>=2 -> disjoint windows.
__global__ void resolve_kernel(const float* __restrict__ grad,
                               const int* __restrict__ cand, const int* __restrict__ cnt,
                               int* __restrict__ cents_i, float* __restrict__ out_cents) {
    __shared__ unsigned char occ[HW];
    __shared__ int scand[C * KCAND];
    __shared__ int scnt[C];
    int b = blockIdx.x;
    int t = threadIdx.x;  // 256 threads
    for (int i = t; i < HW / 4; i += 256) ((int*)occ)[i] = 0;
    for (int i = t; i < C * KCAND; i += 256) scand[i] = cand[b * C * KCAND + i];
    for (int i = t; i < C; i += 256) scnt[i] = cnt[b * C + i];
    __syncthreads();
    int c = t;
    int gi = c / 14, gj = c - 14 * (c / 14);
    int myround = 2 * gi + gj;
    for (int r = 0; r < 40; r++) {
        if (c < C && myround == r) {
            int n = scnt[c];
            int ny = 0, nx = 0;
            bool found = false;
            if (n <= KCAND) {
                for (int k = 0; k < n; k++) {
                    int pos = scand[c * KCAND + k];
                    if (!occ[pos]) {
                        found = true; ny = pos / W; nx = pos - (pos / W) * W;
                        occ[pos] = 1; break;
                    }
                }
            } else {
                // slow path (>KCAND exact ties -- effectively never)
                const float* gb = grad + (size_t)b * HW;
                int cy = 8 + 16 * gi, cx = 8 + 16 * gj;
                int ymin = max(0, cy - NB), ymax = min(H, cy + NB);
                int xmin = max(0, cx - NB), xmax = min(W, cx + NB);
                float mv = INFINITY;
                for (int rr = ymin; rr < ymax; rr++)
                    for (int cc = xmin; cc < xmax; cc++)
                        mv = fminf(mv, gb[rr * W + cc]);
                for (int rr = ymin; rr < ymax && !found; rr++)
                    for (int cc = xmin; cc < xmax && !found; cc++)
                        if (gb[rr * W + cc] == mv && !occ[rr * W + cc]) {
                            found = true; ny = rr; nx = cc; occ[rr * W + cc] = 1;
                        }
            }
            if (!found) { ny = 8 + 16 * gi; nx = 8 + 16 * gj; }
            cents_i[(b * C + c) * 2 + 0] = ny;
            cents_i[(b * C + c) * 2 + 1] = nx;
            out_cents[(b * C + c) * 2 + 0] = (float)ny;
            out_cents[(b * C + c) * 2 + 1] = (float)nx;
        }
        __syncthreads();
    }
}

// ---------------- propagation init / seed ----------------
__global__ void init_kernel(float* __restrict__ dist, short* __restrict__ mask) {
    int idx = blockIdx.x * blockDim.x + threadIdx.x;
    if (idx >= B * HW) return;
    dist[idx] = INFINITY;
    mask[idx] = -1;
}

// serial in c per batch: reproduces XLA scatter later-index-wins on collisions
__global__ void seed_kernel(const int* __restrict__ cents_i,
                            float* __restrict__ dist, short* __restrict__ mask) {
    int b = threadIdx.x;
    if (b >= B) return;
    for (int c = 0; c < C; c++) {
        int cy = cents_i[(b * C + c) * 2 + 0];
        int cx = cents_i[(b * C + c) * 2 + 1];
        size_t q = (size_t)b * HW + cy * W + cx;
        dist[q] = 0.f;
        mask[q] = (short)c;
    }
}

// ---------------- fused propagation: T iterations, register time-skewing ----------------
__device__ __forceinline__ int wrapc(int v) {
    v += (v < 0) ? 224 : 0;
    v -= (v >= 224) ? 224 : 0;
    return v;
}
__device__ __forceinline__ uint2 packm(int a, int b_, int c_, int d_) {
    uint2 r;
    r.x = (a & 0xffff) | (b_ << 16);
    r.y = (c_ & 0xffff) | (d_ << 16);
    return r;
}

template<int DIR>
__device__ __forceinline__ void do_pass(float (&D)[4][4], int (&M)[4][4],
    const float (&Wg)[4][4], const float (&cv)[4][4],
    float4* __restrict__ hd, uint2* __restrict__ hm, int tid, int ty, int tx)
{
    // publish pre-pass boundary values
    float4 pd; uint2 pm;
    if      (DIR == 0) { pd = make_float4(D[0][0],D[0][1],D[0][2],D[0][3]); pm = packm(M[0][0],M[0][1],M[0][2],M[0][3]); }
    else if (DIR == 1) { pd = make_float4(D[3][0],D[3][1],D[3][2],D[3][3]); pm = packm(M[3][0],M[3][1],M[3][2],M[3][3]); }
    else if (DIR == 2) { pd = make_float4(D[0][0],D[1][0],D[2][0],D[3][0]); pm = packm(M[0][0],M[1][0],M[2][0],M[3][0]); }
    else               { pd = make_float4(D[0][3],D[1][3],D[2][3],D[3][3]); pm = packm(M[0][3],M[1][3],M[2][3],M[3][3]); }
    hd[tid] = pd; hm[tid] = pm;
    __syncthreads();
    bool has; int nidx;
    if      (DIR == 0) { has = (ty < 15); nidx = tid + 16; }
    else if (DIR == 1) { has = (ty > 0);  nidx = tid - 16; }
    else if (DIR == 2) { has = (tx < 15); nidx = tid + 1; }
    else               { has = (tx > 0);  nidx = tid - 1; }
    float nb[4]; int nbm[4];
    if (has) {
        float4 t = hd[nidx]; uint2 u = hm[nidx];
        nb[0] = t.x; nb[1] = t.y; nb[2] = t.z; nb[3] = t.w;
        nbm[0] = (int)(short)(u.x & 0xffff); nbm[1] = (int)(short)(u.x >> 16);
        nbm[2] = (int)(short)(u.y & 0xffff); nbm[3] = (int)(short)(u.y >> 16);
    } else {
        nb[0] = nb[1] = nb[2] = nb[3] = INFINITY;
        nbm[0] = nbm[1] = nbm[2] = nbm[3] = 0;
    }
    // in-register update in anti-propagation order (pre-value semantics, no dbuf)
    if (DIR == 0) {
        #pragma unroll
        for (int i = 0; i < 4; i++)
            #pragma unroll
            for (int j = 0; j < 4; j++) {
                float sd = (i < 3) ? D[i+1][j] : nb[j];
                int   sm = (i < 3) ? M[i+1][j] : nbm[j];
                float wd = __fadd_rn(__fadd_rn(sd, Wg[i][j]), cv[i][j]);
                if (wd < D[i][j]) { D[i][j] = wd; M[i][j] = sm; }
            }
    } else if (DIR == 1) {
        #pragma unroll
        for (int i = 3; i >= 0; i--)
            #pragma unroll
            for (int j = 0; j < 4; j++) {
                float sd = (i > 0) ? D[i-1][j] : nb[j];
                int   sm = (i > 0) ? M[i-1][j] : nbm[j];
                float wd = __fadd_rn(__fadd_rn(sd, Wg[i][j]), cv[i][j]);
                if (wd < D[i][j]) { D[i][j] = wd; M[i][j] = sm; }
            }
    } else if (DIR == 2) {
        #pragma unroll
        for (int i = 0; i < 4; i++)
            #pragma unroll
            for (int j = 0; j < 4; j++) {
                float sd = (j < 3) ? D[i][j+1] : nb[i];
                int   sm = (j < 3) ? M[i][j+1] : nbm[i];
                float wd = __fadd_rn(__fadd_rn(sd, Wg[i][j]), cv[i][j]);
                if (wd < D[i][j]) { D[i][j] = wd; M[i][j] = sm; }
            }
    } else {
        #pragma unroll
        for (int i = 0; i < 4; i++)
            #pragma unroll
            for (int j = 3; j >= 0; j--) {
                float sd = (j > 0) ? D[i][j-1] : nb[i];
                int   sm = (j > 0) ? M[i][j-1] : nbm[i];
                float wd = __fadd_rn(__fadd_rn(sd, Wg[i][j]), cv[i][j]);
                if (wd < D[i][j]) { D[i][j] = wd; M[i][j] = sm; }
            }
    }
}

__global__ __launch_bounds__(256) void prop_fused(
    const float* __restrict__ din, const short* __restrict__ min_,
    float* __restrict__ dout, short* __restrict__ mout,
    const float* __restrict__ wgm, const float* __restrict__ cw, int n_it,
    float* __restrict__ out_mask)
{
    __shared__ float4 hd[2][256];
    __shared__ uint2  hm[2][256];
    int blk = blockIdx.x;
    int b = blk >> 4, tile = blk & 15;
    int ty0 = (tile >> 2) * TS, tx0 = (tile & 3) * TS;
    int tid = threadIdx.x;
    int tx = tid & 15, ty = tid >> 4;
    int gx0 = wrapc(tx0 + 4 * tx - 4);
    int rowoff[4];
    #pragma unroll
    for (int i = 0; i < 4; i++) {
        int y = wrapc(ty0 + 4 * ty - 4 + i);
        rowoff[i] = y * W + gx0;
    }
    const float* dinb = din + (size_t)b * HW;
    const short* minb = min_ + (size_t)b * HW;
    const float* wgmb = wgm + (size_t)b * HW;
    float D[4][4]; int M[4][4]; float Wg[4][4];
    #pragma unroll
    for (int i = 0; i < 4; i++) {
        float4 dv = *(const float4*)(dinb + rowoff[i]);
        float4 wv = *(const float4*)(wgmb + rowoff[i]);
        uint2  mv = *(const uint2*)(minb + rowoff[i]);
        D[i][0] = dv.x; D[i][1] = dv.y; D[i][2] = dv.z; D[i][3] = dv.w;
        Wg[i][0] = wv.x; Wg[i][1] = wv.y; Wg[i][2] = wv.z; Wg[i][3] = wv.w;
        M[i][0] = (int)(short)(mv.x & 0xffff); M[i][1] = (int)(short)(mv.x >> 16);
        M[i][2] = (int)(short)(mv.y & 0xffff); M[i][3] = (int)(short)(mv.y >> 16);
    }
    // register-cache all 4 directions' cw tiles (read once per launch)
    float cv[4][4][4];
    #pragma unroll
    for (int d = 0; d < 4; d++) {
        const float* cwd = cw + ((size_t)d * B + b) * HW;
        #pragma unroll
        for (int i = 0; i < 4; i++) {
            float4 t = *(const float4*)(cwd + rowoff[i]);
            cv[d][i][0] = t.x; cv[d][i][1] = t.y; cv[d][i][2] = t.z; cv[d][i][3] = t.w;
        }
    }
    for (int it = 0; it < n_it; ++it) {
        do_pass<0>(D, M, Wg, cv[0], hd[0], hm[0], tid, ty, tx);
        do_pass<1>(D, M, Wg, cv[1], hd[1], hm[1], tid, ty, tx);
        do_pass<2>(D, M, Wg, cv[2], hd[0], hm[0], tid, ty, tx);
        do_pass<3>(D, M, Wg, cv[3], hd[1], hm[1], tid, ty, tx);
    }
    if (ty >= 1 && ty < 15 && tx >= 1 && tx < 15) {
        if (out_mask) {
            float* omb = out_mask + (size_t)b * HW;
            #pragma unroll
            for (int i = 0; i < 4; i++)
                *(float4*)(omb + rowoff[i]) =
                    make_float4((float)M[i][0], (float)M[i][1], (float)M[i][2], (float)M[i][3]);
        } else {
            float* doutb = dout + (size_t)b * HW;
            short* moutb = mout + (size_t)b * HW;
            #pragma unroll
            for (int i = 0; i < 4; i++) {
                *(float4*)(doutb + rowoff[i]) = make_float4(D[i][0], D[i][1], D[i][2], D[i][3]);
                *(uint2*)(moutb + rowoff[i]) = packm(M[i][0], M[i][1], M[i][2], M[i][3]);
            }
        }
    }
}

extern "C" void kernel_launch(void* const* d_in, const int* in_sizes, int n_in,
                              void* d_out, int out_size, void* d_ws, size_t ws_size,
                              hipStream_t stream) {
    const float* x   = (const float*)d_in[0];
    const float* wgt = (const float*)d_in[1];
    float* out = (float*)d_out;
    float* out_grad  = out;
    float* out_cents = out + (size_t)B * HW;
    float* out_mask  = out + (size_t)B * HW + (size_t)B * C * 2;

    char* ws = (char*)d_ws;
    const size_t n = (size_t)B * HW;
    float* wgm    = (float*)ws;                ws += sizeof(float) * n;
    float* cw     = (float*)ws;                ws += sizeof(float) * n * 4;
    float* dist_a = (float*)ws;                ws += sizeof(float) * n;
    float* dist_b = (float*)ws;                ws += sizeof(float) * n;
    short* mask_a = (short*)ws;                ws += sizeof(short) * n;
    short* mask_b = (short*)ws;                ws += sizeof(short) * n;
    int*   cents_i = (int*)ws;                 ws += sizeof(int) * B * C * 2;
    // cand/cnt alias dist_b: only live between cand_kernel and resolve_kernel,
    // before the first prop_fused write of dist_b.
    int* cand = (int*)dist_b;
    int* cnt  = cand + (size_t)B * C * KCAND;

    dim3 blk(256);
    dim3 grd((unsigned)((n + 255) / 256));

    gradcw_kernel<<<grd, blk, 0, stream>>>(x, wgt, wgm, out_grad, cw);
    cand_kernel<<<(B * C) / 4, 256, 0, stream>>>(out_grad, cand, cnt);
    resolve_kernel<<<B, 256, 0, stream>>>(out_grad, cand, cnt, cents_i, out_cents);
    init_kernel<<<grd, blk, 0, stream>>>(dist_a, mask_a);
    seed_kernel<<<1, 64, 0, stream>>>(cents_i, dist_a, mask_a);

    float* da = dist_a; float* db = dist_b;
    short* ma = mask_a; short* mb = mask_b;
    int iters_left = NUM_ITERS;
    while (iters_left > 0) {
        int n_it = iters_left < 4 ? iters_left : 4;
        bool last = (iters_left - n_it) == 0;
        prop_fused<<<B * 16, 256, 0, stream>>>(da, ma, db, mb, wgm, cw, n_it,
                                               last ? out_mask : (float*)nullptr);
        float* td = da; da = db; db = td;
        short* tm = ma; ma = mb; mb = tm;
        iters_left -= n_it;
    }
}